// Round 11
// baseline (33.752 us; speedup 1.0000x reference)
//
#include <hip/hip_runtime.h>

#define SEQ   2048
#define EMB   128
#define NH    16
#define NB    2
#define NBH   (NB * NH)      // 32
#define QB    128            // q rows per block
#define NQB   (SEQ / QB)     // 16
#define SEQ_H 1024           // tokens staged per block (one t-half)
#define K1_THREADS 512

typedef _Float16 half_t;
typedef _Float16 half4  __attribute__((ext_vector_type(4)));
typedef __fp16   fp16x2 __attribute__((ext_vector_type(2)));  // cvt_pkrtz return type
typedef float    floatx16 __attribute__((ext_vector_type(16)));

// LDS carve (aliased, 36944 B total -> 4 blocks/CU):
//   zqk  : half4 [2][1024]              @ 0      (16384 B)  row-major z, K-frags
//   zT   : 10 rows x 2056 B             @ 16384  (20560 B)  transposed z, V-frags
//   red  : float[4352]                  @ 0      (alias, used after final sync)
#define SMEM_BYTES 36944
#define ZT_OFF     16384
#define ZT_PITCH   2056

// exp2 on the VALU pipe (no v_exp): s in [-4.25, 4.25], rel err <= 4.2e-5.
// 8 full-rate VALU ops vs v_exp's trans-pipe slot -> lets both pipes run.
__device__ __forceinline__ float exp2_valu(float s) {
    float n  = __builtin_rintf(s);       // v_rndne_f32
    float f  = s - n;                    // [-0.5, 0.5]
    float pp = fmaf(f, 0.009618130f, 0.055504110f);
    pp = fmaf(f, pp, 0.240226512f);
    pp = fmaf(f, pp, 0.693147182f);
    pp = fmaf(f, pp, 1.0f);
    return ldexpf(pp, (int)n);           // v_cvt_i32 + v_ldexp
}

// Kernel 1: MFMA flash attention partial. Block = (b,h,q-tile,t-half).
// Swapped QK^T (A=K, B=Q) so score regs feed the PV A-operand directly.
// V has a ones-column (d=8) so the row-sum l falls out of the same MFMA.
// Writes UNNORMALIZED partials: D-values (f16) to pD[row][c2][128] (d_out
// as scratch), row-sums (f32) to lbuf[row][c2*16+h] (ws).
__global__ __launch_bounds__(K1_THREADS, 8)
void qattn_mfma_kernel(const float* __restrict__ x,
                       const float* __restrict__ theta,
                       half_t* __restrict__ pD,
                       float* __restrict__ lbuf)
{
    __shared__ __align__(16) char smem[SMEM_BYTES];

    const int tid = threadIdx.x;
    const int bid = blockIdx.x;
    const int c2  = bid & 1;                 // t-half of the sequence
    const int qb  = (bid >> 1) & (NQB - 1);
    const int bh  = bid >> 5;                // 16 qb x 2 c2 blocks share (b,h)
    const int b   = bh >> 4;
    const int h   = bh & (NH - 1);

    float th[8];
#pragma unroll
    for (int d = 0; d < 8; ++d) th[d] = theta[d];

    const float4* x4 = (const float4*)x + (size_t)b * SEQ * (EMB / 4) + h * 2;

    half4* zqk0 = (half4*)smem;             // [t] = z[t][0..3]
    half4* zqk1 = (half4*)(smem + 8192);    // [t] = z[t][4..7]

    // ---- stage z = cos(x+theta) f16 for this t-half: row-major + transposed ----
#pragma unroll
    for (int i = 0; i < SEQ_H / K1_THREADS; ++i) {
        const int tl = tid + i * K1_THREADS;       // local token
        const int tg = c2 * SEQ_H + tl;            // global token
        float4 lo  = x4[(size_t)tg * (EMB / 4)];
        float4 hi4 = x4[(size_t)tg * (EMB / 4) + 1];
        float z0 = __cosf(lo.x  + th[0]);
        float z1 = __cosf(lo.y  + th[1]);
        float z2 = __cosf(lo.z  + th[2]);
        float z3 = __cosf(lo.w  + th[3]);
        float z4 = __cosf(hi4.x + th[4]);
        float z5 = __cosf(hi4.y + th[5]);
        float z6 = __cosf(hi4.z + th[6]);
        float z7 = __cosf(hi4.w + th[7]);
        half4 zl, zh;
        zl[0] = (half_t)z0; zl[1] = (half_t)z1; zl[2] = (half_t)z2; zl[3] = (half_t)z3;
        zh[0] = (half_t)z4; zh[1] = (half_t)z5; zh[2] = (half_t)z6; zh[3] = (half_t)z7;
        zqk0[tl] = zl;
        zqk1[tl] = zh;
#pragma unroll
        for (int d = 0; d < 4; ++d)
            *(half_t*)(smem + ZT_OFF + d * ZT_PITCH + tl * 2) = zl[d];
#pragma unroll
        for (int d = 0; d < 4; ++d)
            *(half_t*)(smem + ZT_OFF + (4 + d) * ZT_PITCH + tl * 2) = zh[d];
        *(half_t*)(smem + ZT_OFF + 8 * ZT_PITCH + tl * 2) = (half_t)1.0f;  // ones -> l
        *(half_t*)(smem + ZT_OFF + 9 * ZT_PITCH + tl * 2) = (half_t)0.0f;  // zero row
    }

    const int lane = tid & 63;
    const int wid  = tid >> 6;      // 0..7
    const int g    = wid & 3;       // q-tile (32 q) within block
    const int c    = wid >> 2;      // sub-half of this block's 1024 t
    const int ln   = lane & 31;
    const int hi   = lane >> 5;

    // Q from global (its token may live in the other t-half's staging).
    // exp(s/sqrt(8)) = exp2(s*C); fold C into Q (|C*z| <= 0.51, f16-safe)
    const float C = 0.35355339059327373f * 1.4426950408889634f;
    const int q = qb * QB + g * 32 + ln;
    float4 xq = ((const float4*)x)[(size_t)(b * SEQ + q) * (EMB / 4) + h * 2 + hi];
    half4 qf;
    qf[0] = (half_t)(__cosf(xq.x + th[4 * hi + 0]) * C);
    qf[1] = (half_t)(__cosf(xq.y + th[4 * hi + 1]) * C);
    qf[2] = (half_t)(__cosf(xq.z + th[4 * hi + 2]) * C);
    qf[3] = (half_t)(__cosf(xq.w + th[4 * hi + 3]) * C);

    __syncthreads();

    const half4* kp  = (hi ? zqk1 : zqk0) + ln;       // kp[t0] = z[t0+ln][4hi..]
    const int    dcl = (ln < 9) ? ln : 9;
    const half4* vp  = (const half4*)(smem + ZT_OFF + dcl * ZT_PITCH + hi * 8);

    floatx16 acc = {};
    const floatx16 zero16 = {};
    const int tb = c * (SEQ_H / 2);

#pragma unroll 4
    for (int tt = 0; tt < SEQ_H / 2; tt += 32) {
        const int t0 = tb + tt;
        half4 kf = kp[t0];
        // s[t_local, q]: q = ln, t_local = (r&3)+8*(r>>2)+4*hi  (scaled scores)
        floatx16 s = __builtin_amdgcn_mfma_f32_32x32x8f16(kf, qf, zero16, 0, 0, 0);
        float p[16];
        // Pipe-split exponentials: 6 on the VALU (poly), 10 on trans (v_exp) --
        // the 134M exps are the core cost; one pipe alone is the bottleneck.
#pragma unroll
        for (int r = 0; r < 16; ++r)
            p[r] = (r < 6) ? exp2_valu(s[r]) : __builtin_amdgcn_exp2f(s[r]);
#pragma unroll
        for (int w = 0; w < 4; ++w) {
            // PV A-frag for t-window w = regs 4w..4w+3
            union { half4 h4; fp16x2 f2[2]; } u;
            u.f2[0] = __builtin_amdgcn_cvt_pkrtz(p[4 * w + 0], p[4 * w + 1]);
            u.f2[1] = __builtin_amdgcn_cvt_pkrtz(p[4 * w + 2], p[4 * w + 3]);
            half4 vf = vp[(t0 >> 2) + 2 * w];
            acc = __builtin_amdgcn_mfma_f32_32x32x8f16(u.h4, vf, acc, 0, 0, 0);
        }
    }

    // ---- combine the 2 sub-halves (LDS alias), write unnormalized partials ----
    __syncthreads();                        // all zqk/zT reads done
    float* red = (float*)smem;
    const int slot = (g * 64 + lane) * 17;  // stride 17: conflict-free
    if (c == 1) {
#pragma unroll
        for (int r = 0; r < 16; ++r) red[slot + r] = acc[r];
    }
    __syncthreads();
    if (c == 0) {
#pragma unroll
        for (int r = 0; r < 16; ++r) acc[r] += red[slot + r];

        const int q0 = qb * QB + g * 32 + 4 * hi;
        if (ln < 8) {
#pragma unroll
            for (int r = 0; r < 16; ++r) {
                const int qq = q0 + (r & 3) + 8 * (r >> 2);
                pD[((size_t)(b * SEQ + qq) * 2 + c2) * EMB + h * 8 + ln] = (half_t)acc[r];
            }
        } else if (ln == 8) {
#pragma unroll
            for (int r = 0; r < 16; ++r) {
                const int qq = q0 + (r & 3) + 8 * (r >> 2);
                lbuf[(size_t)(b * SEQ + qq) * 32 + c2 * 16 + h] = acc[r];
            }
        }
    }
}

// Kernel 2 (MFMA): sum t-half partials, normalize -> Xn f16; W -> f16; then
// out[r][e] = sum_k Xn[r][k] W[e][k] via 32x32x8 f16 MFMA.
#define K2_ROWS    32
#define K2_THREADS 256
#define XW_PITCH   132

__global__ __launch_bounds__(K2_THREADS)
void combine_mfma_kernel(const half_t* pD,
                         const float* __restrict__ lbuf,
                         const float* __restrict__ W,
                         float* out)
{
    __shared__ half_t Ws[128 * XW_PITCH];      // [e][k] f16, 33792 B
    __shared__ half_t Xs[K2_ROWS * XW_PITCH];  // [r][k] f16 normalized, 8448 B

    const int tid   = threadIdx.x;
    const int rbase = blockIdx.x * K2_ROWS;

    // ---- stage W as f16 ----
#pragma unroll
    for (int it = 0; it < 16; ++it) {
        const int idx = tid + it * K2_THREADS;   // 0..4095 float4s
        const int e   = idx >> 5;
        const int k4  = idx & 31;
        float4 w = ((const float4*)W)[idx];
        union { half4 h4; fp16x2 f2[2]; } u;
        u.f2[0] = __builtin_amdgcn_cvt_pkrtz(w.x, w.y);
        u.f2[1] = __builtin_amdgcn_cvt_pkrtz(w.z, w.w);
        *(half4*)&Ws[e * XW_PITCH + 4 * k4] = u.h4;
    }
    // ---- stage Xn = (pD_half0 + pD_half1) / l as f16 ----
#pragma unroll
    for (int it = 0; it < 8; ++it) {
        const int idx = tid + it * K2_THREADS;   // 0..2047: (r, k2)
        const int r   = idx >> 6;
        const int k2  = idx & 63;                // k = 2*k2
        const int row = rbase + r;
        const half_t* p0 = &pD[(size_t)row * 256 + 2 * k2];
        const int hh = k2 >> 2;
        float l  = lbuf[(size_t)row * 32 + hh] + lbuf[(size_t)row * 32 + 16 + hh];
        float rl = __builtin_amdgcn_rcpf(l);
        float v0 = ((float)p0[0] + (float)p0[128]) * rl;
        float v1 = ((float)p0[1] + (float)p0[129]) * rl;
        *(fp16x2*)&Xs[r * XW_PITCH + 2 * k2] = __builtin_amdgcn_cvt_pkrtz(v0, v1);
    }
    __syncthreads();

    const int lane = tid & 63;
    const int wv   = tid >> 6;     // 0..3 -> e-tile
    const int ln   = lane & 31;
    const int hi   = lane >> 5;
    const int e0   = wv * 32;

    floatx16 acc = {};
#pragma unroll
    for (int kk = 0; kk < 16; ++kk) {
        half4 a = *(const half4*)&Xs[ln * XW_PITCH + kk * 8 + hi * 4];          // X[r=ln][k..]
        half4 bf = *(const half4*)&Ws[(e0 + ln) * XW_PITCH + kk * 8 + hi * 4];  // W[e=ln][k..]
        acc = __builtin_amdgcn_mfma_f32_32x32x8f16(a, bf, acc, 0, 0, 0);
    }

    // D: col = e0+ln, row r_loc = (reg&3)+8*(reg>>2)+4*hi -> coalesced stores
#pragma unroll
    for (int reg = 0; reg < 16; ++reg) {
        const int r_loc = (reg & 3) + 8 * (reg >> 2) + 4 * hi;
        out[(size_t)(rbase + r_loc) * EMB + e0 + ln] = acc[reg];
    }
}

extern "C" void kernel_launch(void* const* d_in, const int* in_sizes, int n_in,
                              void* d_out, int out_size, void* d_ws, size_t ws_size,
                              hipStream_t stream) {
    const float* x     = (const float*)d_in[0];
    const float* theta = (const float*)d_in[1];
    const float* W     = (const float*)d_in[2];
    float*  out  = (float*)d_out;
    half_t* pD   = (half_t*)d_out;   // d_out doubles as f16 partial scratch
    float*  lbuf = (float*)d_ws;     // 512 KiB row-sum partials

    qattn_mfma_kernel<<<NBH * NQB * 2, K1_THREADS, 0, stream>>>(x, theta, pD, lbuf);
    combine_mfma_kernel<<<(NB * SEQ) / K2_ROWS, K2_THREADS, 0, stream>>>(pD, lbuf, W, out);
}

// Round 12
// 28.830 us; speedup vs baseline: 1.1707x; 1.1707x over previous
//
#include <hip/hip_runtime.h>

#define SEQ   2048
#define EMB   128
#define NH    16
#define NB    2
#define NBH   (NB * NH)      // 32
#define QB    128            // q rows per block
#define NQB   (SEQ / QB)     // 16
#define SEQ_H 1024           // tokens staged per block (one t-half)
#define K1_THREADS 512

typedef _Float16 half_t;
typedef _Float16 half4  __attribute__((ext_vector_type(4)));
typedef _Float16 half8  __attribute__((ext_vector_type(8)));
typedef __fp16   fp16x2 __attribute__((ext_vector_type(2)));  // cvt_pkrtz return type
typedef int      intx2  __attribute__((ext_vector_type(2)));  // permlane32_swap return
typedef float    floatx16 __attribute__((ext_vector_type(16)));

// LDS carve (aliased, 37024 B total -> 4 blocks/CU):
//   zqk  : half4 [2][1024]              @ 0      (16384 B)  row-major z, K-frags
//   zT   : 10 rows x 2064 B             @ 16384  (20640 B)  transposed z, V-frags
//          pitch 2064 B: 16B-aligned rows (b128-safe), 4-bank shift/row
//   red  : float[4352]                  @ 0      (alias, used after final sync)
#define SMEM_BYTES 37024
#define ZT_OFF     16384
#define ZT_PITCH   2064

// Kernel 1: MFMA flash attention partial. Block = (b,h,q-tile,t-half).
// Swapped QK^T (A=K, B=Q) so score regs feed the PV A-operand directly.
// PV uses 32x32x16 (native gfx950 shape): the K=16 A-frag is assembled from
// the K=8-layout score regs with 2 permlane32_swap per 16 tokens.
// V has a ones-column (d=8) so the row-sum l falls out of the same MFMA.
__global__ __launch_bounds__(K1_THREADS, 6)
void qattn_mfma_kernel(const float* __restrict__ x,
                       const float* __restrict__ theta,
                       half_t* __restrict__ pD,
                       float* __restrict__ lbuf)
{
    __shared__ __align__(16) char smem[SMEM_BYTES];

    const int tid = threadIdx.x;
    const int bid = blockIdx.x;
    const int c2  = bid & 1;                 // t-half of the sequence
    const int qb  = (bid >> 1) & (NQB - 1);
    const int bh  = bid >> 5;                // 16 qb x 2 c2 blocks share (b,h)
    const int b   = bh >> 4;
    const int h   = bh & (NH - 1);

    float th[8];
#pragma unroll
    for (int d = 0; d < 8; ++d) th[d] = theta[d];

    const float4* x4 = (const float4*)x + (size_t)b * SEQ * (EMB / 4) + h * 2;

    half4* zqk0 = (half4*)smem;             // [t] = z[t][0..3]
    half4* zqk1 = (half4*)(smem + 8192);    // [t] = z[t][4..7]

    // ---- stage z = cos(x+theta) f16 for this t-half: row-major + transposed ----
#pragma unroll
    for (int i = 0; i < SEQ_H / K1_THREADS; ++i) {
        const int tl = tid + i * K1_THREADS;       // local token
        const int tg = c2 * SEQ_H + tl;            // global token
        float4 lo  = x4[(size_t)tg * (EMB / 4)];
        float4 hi4 = x4[(size_t)tg * (EMB / 4) + 1];
        float z0 = __cosf(lo.x  + th[0]);
        float z1 = __cosf(lo.y  + th[1]);
        float z2 = __cosf(lo.z  + th[2]);
        float z3 = __cosf(lo.w  + th[3]);
        float z4 = __cosf(hi4.x + th[4]);
        float z5 = __cosf(hi4.y + th[5]);
        float z6 = __cosf(hi4.z + th[6]);
        float z7 = __cosf(hi4.w + th[7]);
        half4 zl, zh;
        zl[0] = (half_t)z0; zl[1] = (half_t)z1; zl[2] = (half_t)z2; zl[3] = (half_t)z3;
        zh[0] = (half_t)z4; zh[1] = (half_t)z5; zh[2] = (half_t)z6; zh[3] = (half_t)z7;
        zqk0[tl] = zl;
        zqk1[tl] = zh;
#pragma unroll
        for (int d = 0; d < 4; ++d)
            *(half_t*)(smem + ZT_OFF + d * ZT_PITCH + tl * 2) = zl[d];
#pragma unroll
        for (int d = 0; d < 4; ++d)
            *(half_t*)(smem + ZT_OFF + (4 + d) * ZT_PITCH + tl * 2) = zh[d];
        *(half_t*)(smem + ZT_OFF + 8 * ZT_PITCH + tl * 2) = (half_t)1.0f;  // ones -> l
        *(half_t*)(smem + ZT_OFF + 9 * ZT_PITCH + tl * 2) = (half_t)0.0f;  // zero row
    }

    const int lane = tid & 63;
    const int wid  = tid >> 6;      // 0..7
    const int g    = wid & 3;       // q-tile (32 q) within block
    const int c    = wid >> 2;      // sub-half of this block's 1024 t
    const int ln   = lane & 31;
    const int hi   = lane >> 5;

    // Q from global (its token may live in the other t-half's staging).
    // exp(s/sqrt(8)) = exp2(s*C); fold C into Q (|C*z| <= 0.51, f16-safe)
    const float C = 0.35355339059327373f * 1.4426950408889634f;
    const int q = qb * QB + g * 32 + ln;
    float4 xq = ((const float4*)x)[(size_t)(b * SEQ + q) * (EMB / 4) + h * 2 + hi];
    half4 qf;
    qf[0] = (half_t)(__cosf(xq.x + th[4 * hi + 0]) * C);
    qf[1] = (half_t)(__cosf(xq.y + th[4 * hi + 1]) * C);
    qf[2] = (half_t)(__cosf(xq.z + th[4 * hi + 2]) * C);
    qf[3] = (half_t)(__cosf(xq.w + th[4 * hi + 3]) * C);

    __syncthreads();

    const half4* kp    = (hi ? zqk1 : zqk0) + ln;     // kp[t0] = z[t0+ln][4hi..]
    const int    dcl   = (ln < 9) ? ln : 9;
    const char*  vbase = smem + ZT_OFF + dcl * ZT_PITCH;

    floatx16 acc = {};
    const floatx16 zero16 = {};
    const int tb = c * (SEQ_H / 2);

#pragma unroll 4
    for (int tt = 0; tt < SEQ_H / 2; tt += 32) {
        const int t0 = tb + tt;
        half4 kf = kp[t0];
        // s[t_local, q]: q = ln, t_local = (r&3)+8*(r>>2)+4*hi  (scaled scores)
        floatx16 s = __builtin_amdgcn_mfma_f32_32x32x8f16(kf, qf, zero16, 0, 0, 0);
        // exp + pack: c[j] = f16(p[2j], p[2j+1]); tokens of c[j] (local, +4hi):
        //   c0:{0,1} c1:{2,3} c2:{8,9} c3:{10,11} c4:{16,17} c5:{18,19} c6:{24,25} c7:{26,27}
        int cpk[8];
#pragma unroll
        for (int j = 0; j < 8; ++j) {
            union { fp16x2 f2; int u; } cv;
            cv.f2 = __builtin_amdgcn_cvt_pkrtz(__builtin_amdgcn_exp2f(s[2 * j]),
                                               __builtin_amdgcn_exp2f(s[2 * j + 1]));
            cpk[j] = cv.u;
        }
        // K=16 A-frags via permlane32_swap: {o0,o1}=swap(a,b):
        //   o0 = {a.lo31, b.lo31}, o1 = {a.hi31, b.hi31}
        // frag1 (t 0..15):  [s02.x, s13.x, s02.y, s13.y]
        // frag2 (t 16..31): [s46.x, s57.x, s46.y, s57.y]
        intx2 s02 = __builtin_amdgcn_permlane32_swap(cpk[0], cpk[2], false, false);
        intx2 s13 = __builtin_amdgcn_permlane32_swap(cpk[1], cpk[3], false, false);
        intx2 s46 = __builtin_amdgcn_permlane32_swap(cpk[4], cpk[6], false, false);
        intx2 s57 = __builtin_amdgcn_permlane32_swap(cpk[5], cpk[7], false, false);
        union { half8 h8; int u[4]; } a1, a2;
        a1.u[0] = s02.x; a1.u[1] = s13.x; a1.u[2] = s02.y; a1.u[3] = s13.y;
        a2.u[0] = s46.x; a2.u[1] = s57.x; a2.u[2] = s46.y; a2.u[3] = s57.y;
        // B-frags: V[t0+8hi+i][dcl] (i=0..7) -> one b128 per MFMA
        half8 v1 = *(const half8*)(vbase + (t0 + 8 * hi) * 2);
        half8 v2 = *(const half8*)(vbase + (t0 + 16 + 8 * hi) * 2);
        acc = __builtin_amdgcn_mfma_f32_32x32x16_f16(a1.h8, v1, acc, 0, 0, 0);
        acc = __builtin_amdgcn_mfma_f32_32x32x16_f16(a2.h8, v2, acc, 0, 0, 0);
    }

    // ---- combine the 2 sub-halves (LDS alias), write unnormalized partials ----
    __syncthreads();                        // all zqk/zT reads done
    float* red = (float*)smem;
    const int slot = (g * 64 + lane) * 17;  // stride 17: conflict-free
    if (c == 1) {
#pragma unroll
        for (int r = 0; r < 16; ++r) red[slot + r] = acc[r];
    }
    __syncthreads();
    if (c == 0) {
#pragma unroll
        for (int r = 0; r < 16; ++r) acc[r] += red[slot + r];

        const int q0 = qb * QB + g * 32 + 4 * hi;
        if (ln < 8) {
#pragma unroll
            for (int r = 0; r < 16; ++r) {
                const int qq = q0 + (r & 3) + 8 * (r >> 2);
                pD[((size_t)(b * SEQ + qq) * 2 + c2) * EMB + h * 8 + ln] = (half_t)acc[r];
            }
        } else if (ln == 8) {
#pragma unroll
            for (int r = 0; r < 16; ++r) {
                const int qq = q0 + (r & 3) + 8 * (r >> 2);
                lbuf[(size_t)(b * SEQ + qq) * 32 + c2 * 16 + h] = acc[r];
            }
        }
    }
}

// Kernel 2 (MFMA): sum t-half partials, normalize -> Xn f16; W -> f16; then
// out[r][e] = sum_k Xn[r][k] W[e][k] via 32x32x8 f16 MFMA.
#define K2_ROWS    32
#define K2_THREADS 256
#define XW_PITCH   132

__global__ __launch_bounds__(K2_THREADS)
void combine_mfma_kernel(const half_t* pD,
                         const float* __restrict__ lbuf,
                         const float* __restrict__ W,
                         float* out)
{
    __shared__ half_t Ws[128 * XW_PITCH];      // [e][k] f16, 33792 B
    __shared__ half_t Xs[K2_ROWS * XW_PITCH];  // [r][k] f16 normalized, 8448 B

    const int tid   = threadIdx.x;
    const int rbase = blockIdx.x * K2_ROWS;

    // ---- stage W as f16 ----
#pragma unroll
    for (int it = 0; it < 16; ++it) {
        const int idx = tid + it * K2_THREADS;   // 0..4095 float4s
        const int e   = idx >> 5;
        const int k4  = idx & 31;
        float4 w = ((const float4*)W)[idx];
        union { half4 h4; fp16x2 f2[2]; } u;
        u.f2[0] = __builtin_amdgcn_cvt_pkrtz(w.x, w.y);
        u.f2[1] = __builtin_amdgcn_cvt_pkrtz(w.z, w.w);
        *(half4*)&Ws[e * XW_PITCH + 4 * k4] = u.h4;
    }
    // ---- stage Xn = (pD_half0 + pD_half1) / l as f16 ----
#pragma unroll
    for (int it = 0; it < 8; ++it) {
        const int idx = tid + it * K2_THREADS;   // 0..2047: (r, k2)
        const int r   = idx >> 6;
        const int k2  = idx & 63;                // k = 2*k2
        const int row = rbase + r;
        const half_t* p0 = &pD[(size_t)row * 256 + 2 * k2];
        const int hh = k2 >> 2;
        float l  = lbuf[(size_t)row * 32 + hh] + lbuf[(size_t)row * 32 + 16 + hh];
        float rl = __builtin_amdgcn_rcpf(l);
        float v0 = ((float)p0[0] + (float)p0[128]) * rl;
        float v1 = ((float)p0[1] + (float)p0[129]) * rl;
        *(fp16x2*)&Xs[r * XW_PITCH + 2 * k2] = __builtin_amdgcn_cvt_pkrtz(v0, v1);
    }
    __syncthreads();

    const int lane = tid & 63;
    const int wv   = tid >> 6;     // 0..3 -> e-tile
    const int ln   = lane & 31;
    const int hi   = lane >> 5;
    const int e0   = wv * 32;

    floatx16 acc = {};
#pragma unroll
    for (int kk = 0; kk < 16; ++kk) {
        half4 a = *(const half4*)&Xs[ln * XW_PITCH + kk * 8 + hi * 4];          // X[r=ln][k..]
        half4 bf = *(const half4*)&Ws[(e0 + ln) * XW_PITCH + kk * 8 + hi * 4];  // W[e=ln][k..]
        acc = __builtin_amdgcn_mfma_f32_32x32x8f16(a, bf, acc, 0, 0, 0);
    }

    // D: col = e0+ln, row r_loc = (reg&3)+8*(reg>>2)+4*hi -> coalesced stores
#pragma unroll
    for (int reg = 0; reg < 16; ++reg) {
        const int r_loc = (reg & 3) + 8 * (reg >> 2) + 4 * hi;
        out[(size_t)(rbase + r_loc) * EMB + e0 + ln] = acc[reg];
    }
}

extern "C" void kernel_launch(void* const* d_in, const int* in_sizes, int n_in,
                              void* d_out, int out_size, void* d_ws, size_t ws_size,
                              hipStream_t stream) {
    const float* x     = (const float*)d_in[0];
    const float* theta = (const float*)d_in[1];
    const float* W     = (const float*)d_in[2];
    float*  out  = (float*)d_out;
    half_t* pD   = (half_t*)d_out;   // d_out doubles as f16 partial scratch
    float*  lbuf = (float*)d_ws;     // 512 KiB row-sum partials

    qattn_mfma_kernel<<<NBH * NQB * 2, K1_THREADS, 0, stream>>>(x, theta, pD, lbuf);
    combine_mfma_kernel<<<(NB * SEQ) / K2_ROWS, K2_THREADS, 0, stream>>>(pD, lbuf, W, out);
}

// Round 13
// 28.131 us; speedup vs baseline: 1.1998x; 1.0248x over previous
//
#include <hip/hip_runtime.h>

#define SEQ   2048
#define EMB   128
#define NH    16
#define NB    2
#define NBH   (NB * NH)      // 32
#define QB    128            // q rows per block
#define NQB   (SEQ / QB)     // 16
#define SEQ_H 1024           // tokens staged per block (one t-half)
#define K1_THREADS 512

typedef _Float16 half_t;
typedef _Float16 half4  __attribute__((ext_vector_type(4)));
typedef __fp16   fp16x2 __attribute__((ext_vector_type(2)));  // cvt_pkrtz return type
typedef float    floatx16 __attribute__((ext_vector_type(16)));

// LDS carve (aliased, 36944 B total -> 4 blocks/CU):
//   zqk  : half4 [2][1024]              @ 0      (16384 B)  row-major z, K-frags
//   zT   : 10 rows x 2056 B             @ 16384  (20560 B)  transposed z, V-frags
//   red  : float[4352]                  @ 0      (alias, used after final sync)
#define SMEM_BYTES 36944
#define ZT_OFF     16384
#define ZT_PITCH   2056

// Kernel 1: MFMA flash attention partial. Block = (b,h,q-tile,t-half).
// Swapped QK^T (A=K, B=Q) so score regs feed the PV A-operand directly.
// V has a ones-column (d=8) so the row-sum l falls out of the same MFMA.
// launch_bounds min-waves=4 (NOT 8): the 64-VGPR cap at 8 forced scratch
// spills of the unrolled loop body -- the hidden ~200-instr VALU stream.
// unroll 1: keep live ranges of p[16]/frags to a single iteration.
__global__ __launch_bounds__(K1_THREADS, 4)
void qattn_mfma_kernel(const float* __restrict__ x,
                       const float* __restrict__ theta,
                       half_t* __restrict__ pD,
                       float* __restrict__ lbuf)
{
    __shared__ __align__(16) char smem[SMEM_BYTES];

    const int tid = threadIdx.x;
    const int bid = blockIdx.x;
    const int c2  = bid & 1;                 // t-half of the sequence
    const int qb  = (bid >> 1) & (NQB - 1);
    const int bh  = bid >> 5;                // 16 qb x 2 c2 blocks share (b,h)
    const int b   = bh >> 4;
    const int h   = bh & (NH - 1);

    float th[8];
#pragma unroll
    for (int d = 0; d < 8; ++d) th[d] = theta[d];

    const float4* x4 = (const float4*)x + (size_t)b * SEQ * (EMB / 4) + h * 2;

    half4* zqk0 = (half4*)smem;             // [t] = z[t][0..3]
    half4* zqk1 = (half4*)(smem + 8192);    // [t] = z[t][4..7]

    // ---- stage z = cos(x+theta) f16 for this t-half: row-major + transposed ----
#pragma unroll
    for (int i = 0; i < SEQ_H / K1_THREADS; ++i) {
        const int tl = tid + i * K1_THREADS;       // local token
        const int tg = c2 * SEQ_H + tl;            // global token
        float4 lo  = x4[(size_t)tg * (EMB / 4)];
        float4 hi4 = x4[(size_t)tg * (EMB / 4) + 1];
        float z0 = __cosf(lo.x  + th[0]);
        float z1 = __cosf(lo.y  + th[1]);
        float z2 = __cosf(lo.z  + th[2]);
        float z3 = __cosf(lo.w  + th[3]);
        float z4 = __cosf(hi4.x + th[4]);
        float z5 = __cosf(hi4.y + th[5]);
        float z6 = __cosf(hi4.z + th[6]);
        float z7 = __cosf(hi4.w + th[7]);
        half4 zl, zh;
        zl[0] = (half_t)z0; zl[1] = (half_t)z1; zl[2] = (half_t)z2; zl[3] = (half_t)z3;
        zh[0] = (half_t)z4; zh[1] = (half_t)z5; zh[2] = (half_t)z6; zh[3] = (half_t)z7;
        zqk0[tl] = zl;
        zqk1[tl] = zh;
#pragma unroll
        for (int d = 0; d < 4; ++d)
            *(half_t*)(smem + ZT_OFF + d * ZT_PITCH + tl * 2) = zl[d];
#pragma unroll
        for (int d = 0; d < 4; ++d)
            *(half_t*)(smem + ZT_OFF + (4 + d) * ZT_PITCH + tl * 2) = zh[d];
        *(half_t*)(smem + ZT_OFF + 8 * ZT_PITCH + tl * 2) = (half_t)1.0f;  // ones -> l
        *(half_t*)(smem + ZT_OFF + 9 * ZT_PITCH + tl * 2) = (half_t)0.0f;  // zero row
    }

    const int lane = tid & 63;
    const int wid  = tid >> 6;      // 0..7
    const int g    = wid & 3;       // q-tile (32 q) within block
    const int c    = wid >> 2;      // sub-half of this block's 1024 t
    const int ln   = lane & 31;
    const int hi   = lane >> 5;

    // Q from global (its token may live in the other t-half's staging).
    // exp(s/sqrt(8)) = exp2(s*C); fold C into Q (|C*z| <= 0.51, f16-safe)
    const float C = 0.35355339059327373f * 1.4426950408889634f;
    const int q = qb * QB + g * 32 + ln;
    float4 xq = ((const float4*)x)[(size_t)(b * SEQ + q) * (EMB / 4) + h * 2 + hi];
    half4 qf;
    qf[0] = (half_t)(__cosf(xq.x + th[4 * hi + 0]) * C);
    qf[1] = (half_t)(__cosf(xq.y + th[4 * hi + 1]) * C);
    qf[2] = (half_t)(__cosf(xq.z + th[4 * hi + 2]) * C);
    qf[3] = (half_t)(__cosf(xq.w + th[4 * hi + 3]) * C);

    __syncthreads();

    const half4* kp  = (hi ? zqk1 : zqk0) + ln;       // kp[t0] = z[t0+ln][4hi..]
    const int    dcl = (ln < 9) ? ln : 9;
    const half4* vp  = (const half4*)(smem + ZT_OFF + dcl * ZT_PITCH + hi * 8);

    floatx16 acc = {};
    const floatx16 zero16 = {};
    const int tb = c * (SEQ_H / 2);

#pragma unroll 1
    for (int tt = 0; tt < SEQ_H / 2; tt += 32) {
        const int t0 = tb + tt;
        half4 kf = kp[t0];
        // s[t_local, q]: q = ln, t_local = (r&3)+8*(r>>2)+4*hi  (scaled scores)
        floatx16 s = __builtin_amdgcn_mfma_f32_32x32x8f16(kf, qf, zero16, 0, 0, 0);
        float p[16];
#pragma unroll
        for (int r = 0; r < 16; ++r) p[r] = __builtin_amdgcn_exp2f(s[r]);
#pragma unroll
        for (int w = 0; w < 4; ++w) {
            // PV A-frag for t-window w = regs 4w..4w+3
            union { half4 h4; fp16x2 f2[2]; } u;
            u.f2[0] = __builtin_amdgcn_cvt_pkrtz(p[4 * w + 0], p[4 * w + 1]);
            u.f2[1] = __builtin_amdgcn_cvt_pkrtz(p[4 * w + 2], p[4 * w + 3]);
            half4 vf = vp[(t0 >> 2) + 2 * w];
            acc = __builtin_amdgcn_mfma_f32_32x32x8f16(u.h4, vf, acc, 0, 0, 0);
        }
    }

    // ---- combine the 2 sub-halves (LDS alias), write unnormalized partials ----
    __syncthreads();                        // all zqk/zT reads done
    float* red = (float*)smem;
    const int slot = (g * 64 + lane) * 17;  // stride 17: conflict-free
    if (c == 1) {
#pragma unroll
        for (int r = 0; r < 16; ++r) red[slot + r] = acc[r];
    }
    __syncthreads();
    if (c == 0) {
#pragma unroll
        for (int r = 0; r < 16; ++r) acc[r] += red[slot + r];

        const int q0 = qb * QB + g * 32 + 4 * hi;
        if (ln < 8) {
#pragma unroll
            for (int r = 0; r < 16; ++r) {
                const int qq = q0 + (r & 3) + 8 * (r >> 2);
                pD[((size_t)(b * SEQ + qq) * 2 + c2) * EMB + h * 8 + ln] = (half_t)acc[r];
            }
        } else if (ln == 8) {
#pragma unroll
            for (int r = 0; r < 16; ++r) {
                const int qq = q0 + (r & 3) + 8 * (r >> 2);
                lbuf[(size_t)(b * SEQ + qq) * 32 + c2 * 16 + h] = acc[r];
            }
        }
    }
}

// Kernel 2 (MFMA): sum t-half partials, normalize -> Xn f16; W -> f16; then
// out[r][e] = sum_k Xn[r][k] W[e][k] via 32x32x8 f16 MFMA.
#define K2_ROWS    32
#define K2_THREADS 256
#define XW_PITCH   132

__global__ __launch_bounds__(K2_THREADS)
void combine_mfma_kernel(const half_t* pD,
                         const float* __restrict__ lbuf,
                         const float* __restrict__ W,
                         float* out)
{
    __shared__ half_t Ws[128 * XW_PITCH];      // [e][k] f16, 33792 B
    __shared__ half_t Xs[K2_ROWS * XW_PITCH];  // [r][k] f16 normalized, 8448 B

    const int tid   = threadIdx.x;
    const int rbase = blockIdx.x * K2_ROWS;

    // ---- stage W as f16 ----
#pragma unroll
    for (int it = 0; it < 16; ++it) {
        const int idx = tid + it * K2_THREADS;   // 0..4095 float4s
        const int e   = idx >> 5;
        const int k4  = idx & 31;
        float4 w = ((const float4*)W)[idx];
        union { half4 h4; fp16x2 f2[2]; } u;
        u.f2[0] = __builtin_amdgcn_cvt_pkrtz(w.x, w.y);
        u.f2[1] = __builtin_amdgcn_cvt_pkrtz(w.z, w.w);
        *(half4*)&Ws[e * XW_PITCH + 4 * k4] = u.h4;
    }
    // ---- stage Xn = (pD_half0 + pD_half1) / l as f16 ----
#pragma unroll
    for (int it = 0; it < 8; ++it) {
        const int idx = tid + it * K2_THREADS;   // 0..2047: (r, k2)
        const int r   = idx >> 6;
        const int k2  = idx & 63;                // k = 2*k2
        const int row = rbase + r;
        const half_t* p0 = &pD[(size_t)row * 256 + 2 * k2];
        const int hh = k2 >> 2;
        float l  = lbuf[(size_t)row * 32 + hh] + lbuf[(size_t)row * 32 + 16 + hh];
        float rl = __builtin_amdgcn_rcpf(l);
        float v0 = ((float)p0[0] + (float)p0[128]) * rl;
        float v1 = ((float)p0[1] + (float)p0[129]) * rl;
        *(fp16x2*)&Xs[r * XW_PITCH + 2 * k2] = __builtin_amdgcn_cvt_pkrtz(v0, v1);
    }
    __syncthreads();

    const int lane = tid & 63;
    const int wv   = tid >> 6;     // 0..3 -> e-tile
    const int ln   = lane & 31;
    const int hi   = lane >> 5;
    const int e0   = wv * 32;

    floatx16 acc = {};
#pragma unroll
    for (int kk = 0; kk < 16; ++kk) {
        half4 a = *(const half4*)&Xs[ln * XW_PITCH + kk * 8 + hi * 4];          // X[r=ln][k..]
        half4 bf = *(const half4*)&Ws[(e0 + ln) * XW_PITCH + kk * 8 + hi * 4];  // W[e=ln][k..]
        acc = __builtin_amdgcn_mfma_f32_32x32x8f16(a, bf, acc, 0, 0, 0);
    }

    // D: col = e0+ln, row r_loc = (reg&3)+8*(reg>>2)+4*hi -> coalesced stores
#pragma unroll
    for (int reg = 0; reg < 16; ++reg) {
        const int r_loc = (reg & 3) + 8 * (reg >> 2) + 4 * hi;
        out[(size_t)(rbase + r_loc) * EMB + e0 + ln] = acc[reg];
    }
}

extern "C" void kernel_launch(void* const* d_in, const int* in_sizes, int n_in,
                              void* d_out, int out_size, void* d_ws, size_t ws_size,
                              hipStream_t stream) {
    const float* x     = (const float*)d_in[0];
    const float* theta = (const float*)d_in[1];
    const float* W     = (const float*)d_in[2];
    float*  out  = (float*)d_out;
    half_t* pD   = (half_t*)d_out;   // d_out doubles as f16 partial scratch
    float*  lbuf = (float*)d_ws;     // 512 KiB row-sum partials

    qattn_mfma_kernel<<<NBH * NQB * 2, K1_THREADS, 0, stream>>>(x, theta, pD, lbuf);
    combine_mfma_kernel<<<(NB * SEQ) / K2_ROWS, K2_THREADS, 0, stream>>>(pD, lbuf, W, out);
}